// Round 1
// baseline (87.806 us; speedup 1.0000x reference)
//
#include <hip/hip_runtime.h>
#include <math.h>

#define HW    9216      // 96*96
#define NPIX  18432     // B*HW
#define NKEY  8192
#define NC    16        // key chunks
#define KPC   (NKEY/NC) // 512 keys per chunk

// ws layout (float units)
#define OFF_Q    0                      // [NPIX][4]
#define OFF_KV   (OFF_Q + NPIX*4)       // [NKEY][6]
#define OFF_EEHS (OFF_KV + NKEY*6)      // [NPIX][8]  : EE0..2,S | HH0..2,pad
#define OFF_MM   (OFF_EEHS + NPIX*8)    // [72][2]    : per-block S min,max
#define OFF_PART (OFF_MM + 144)         // [NC][NPIX][4] : s, sv0, sv1, sv2

__device__ __forceinline__ float gelu_tanh(float x){
    float u = 0.7978845608028654f*(x + 0.044715f*x*x*x);
    return 0.5f*x*(1.0f + tanhf(u));
}

__global__ __launch_bounds__(256) void k1_prep(
    const float* __restrict__ front, const float* __restrict__ back,
    const float* __restrict__ bg,
    const float* __restrict__ mi_w1, const float* __restrict__ mi_b1,
    const float* __restrict__ mi_w2, const float* __restrict__ mi_b2,
    const float* __restrict__ q_w,  const float* __restrict__ k_w,
    const float* __restrict__ v_w,
    const float* __restrict__ n1_g, const float* __restrict__ n1_b,
    const float* __restrict__ e_w,  const float* __restrict__ e_b,
    const float* __restrict__ f_w,  const float* __restrict__ f_b,
    const float* __restrict__ g_w,  const float* __restrict__ g_b,
    const float* __restrict__ h_w,  const float* __restrict__ h_b,
    float* __restrict__ ws)
{
    float* ws_q    = ws + OFF_Q;
    float* ws_kv   = ws + OFF_KV;
    float* ws_eehs = ws + OFF_EEHS;
    float* ws_mm   = ws + OFF_MM;

    int tid = threadIdx.x;
    int pix = blockIdx.x*256 + tid;      // 0..18431

    // ---------- keys: k,v from codebook ----------
    if (pix < NKEY){
        float c0 = bg[pix], c1 = bg[NKEY+pix], c2 = bg[2*NKEY+pix];
        #pragma unroll
        for (int i=0;i<3;i++){
            ws_kv[pix*6+i]   = k_w[i*3+0]*c0 + k_w[i*3+1]*c1 + k_w[i*3+2]*c2;
            ws_kv[pix*6+3+i] = v_w[i*3+0]*c0 + v_w[i*3+1]*c1 + v_w[i*3+2]*c2;
        }
    }

    int b   = (pix >= HW) ? 1 : 0;
    int pos = pix - b*HW;
    int y   = pos / 96;
    int x   = pos - y*96;
    const float* fbase = front + b*3*HW;
    const float* bbase = back  + b*3*HW;

    // ---------- 7x7 zero-padded box sums ----------
    float s1f[3]={0,0,0}, s2f[3]={0,0,0}, s1b[3]={0,0,0}, s2b[3]={0,0,0};
    for (int dy=-3; dy<=3; ++dy){
        int yy = y+dy;
        if (yy < 0 || yy >= 96) continue;
        for (int dx=-3; dx<=3; ++dx){
            int xx = x+dx;
            if (xx < 0 || xx >= 96) continue;
            int off = yy*96+xx;
            #pragma unroll
            for (int c=0;c<3;c++){
                float fv = fbase[c*HW+off];
                float bv = bbase[c*HW+off];
                s1f[c]+=fv; s2f[c]+=fv*fv;
                s1b[c]+=bv; s2b[c]+=bv*bv;
            }
        }
    }

    float xnf[3], adain[3], bn[3], bval[3];
    #pragma unroll
    for (int c=0;c<3;c++){
        float mf = s1f[c]*(1.0f/49.0f);
        float vf = (s2f[c] - s1f[c]*s1f[c]*(1.0f/49.0f))*(1.0f/48.0f);
        float fv = fbase[c*HW+pos];
        xnf[c] = (fv - mf)/(sqrtf(vf)+1e-8f);

        float mb = s1b[c]*(1.0f/49.0f);
        float vb = (s2b[c] - s1b[c]*s1b[c]*(1.0f/49.0f))*(1.0f/48.0f);
        float bb = bbase[c*HW+pos];
        bval[c]  = bb;
        float stdb = sqrtf(vb);
        adain[c] = xnf[c]*stdb + mb;         // no eps on y_std
        bn[c]    = (bb - mb)/(stdb + 1e-8f);
    }

    float EE[3], FF[3], GG[3], HHv[3];
    #pragma unroll
    for (int i=0;i<3;i++){
        EE[i]  = e_w[i*3+0]*adain[0] + e_w[i*3+1]*adain[1] + e_w[i*3+2]*adain[2] + e_b[i];
        FF[i]  = f_w[i*3+0]*xnf[0]   + f_w[i*3+1]*xnf[1]   + f_w[i*3+2]*xnf[2]   + f_b[i];
        GG[i]  = g_w[i*3+0]*bn[0]    + g_w[i*3+1]*bn[1]    + g_w[i*3+2]*bn[2]    + g_b[i];
        HHv[i] = h_w[i*3+0]*bval[0]  + h_w[i*3+1]*bval[1]  + h_w[i*3+2]*bval[2]  + h_b[i];
    }
    float num = FF[0]*GG[0]+FF[1]*GG[1]+FF[2]*GG[2];
    float fn  = sqrtf(FF[0]*FF[0]+FF[1]*FF[1]+FF[2]*FF[2]);
    float gn  = sqrtf(GG[0]*GG[0]+GG[1]*GG[1]+GG[2]*GG[2]);
    float S   = num/(fn*gn);

    float4* eehs4 = (float4*)ws_eehs;
    eehs4[pix*2+0] = make_float4(EE[0],EE[1],EE[2],S);
    eehs4[pix*2+1] = make_float4(HHv[0],HHv[1],HHv[2],0.0f);

    // ---------- per-block S min/max (each block is within one batch: 9216/256=36) ----------
    __shared__ float smn[256], smx[256];
    smn[tid]=S; smx[tid]=S; __syncthreads();
    for (int s=128; s>0; s>>=1){
        if (tid<s){ smn[tid]=fminf(smn[tid],smn[tid+s]); smx[tid]=fmaxf(smx[tid],smx[tid+s]); }
        __syncthreads();
    }
    if (tid==0){ ws_mm[blockIdx.x*2+0]=smn[0]; ws_mm[blockIdx.x*2+1]=smx[0]; }

    // ---------- token q : mlp_in -> ln -> q_w, pre-scaled by scale*log2e ----------
    float xt0 = fbase[0*HW+pos], xt1 = fbase[1*HW+pos], xt2 = fbase[2*HW+pos];
    float h6[6];
    #pragma unroll
    for (int i=0;i<6;i++){
        float a = mi_w1[i*3+0]*xt0 + mi_w1[i*3+1]*xt1 + mi_w1[i*3+2]*xt2 + mi_b1[i];
        h6[i] = gelu_tanh(a);
    }
    float x2[3];
    #pragma unroll
    for (int i=0;i<3;i++){
        float a = mi_b2[i];
        #pragma unroll
        for (int k=0;k<6;k++) a += mi_w2[i*6+k]*h6[k];
        x2[i]=a;
    }
    float m  = (x2[0]+x2[1]+x2[2])*(1.0f/3.0f);
    float d0 = x2[0]-m, d1 = x2[1]-m, d2 = x2[2]-m;
    float var = (d0*d0+d1*d1+d2*d2)*(1.0f/3.0f);
    float inv = 1.0f/sqrtf(var+1e-5f);
    float xn0 = d0*inv*n1_g[0]+n1_b[0];
    float xn1 = d1*inv*n1_g[1]+n1_b[1];
    float xn2 = d2*inv*n1_g[2]+n1_b[2];
    const float qs = 0.5773502691896258f * 1.4426950408889634f; // d^-0.5 * log2(e)
    float4 qv;
    qv.x = (q_w[0]*xn0 + q_w[1]*xn1 + q_w[2]*xn2)*qs;
    qv.y = (q_w[3]*xn0 + q_w[4]*xn1 + q_w[5]*xn2)*qs;
    qv.z = (q_w[6]*xn0 + q_w[7]*xn1 + q_w[8]*xn2)*qs;
    qv.w = 0.0f;
    ((float4*)ws_q)[pix] = qv;
}

__global__ __launch_bounds__(256) void k2_attn(const float* __restrict__ ws)
{
    const float* ws_q  = ws + OFF_Q;
    const float* ws_kv = ws + OFF_KV;
    float* ws_part     = (float*)(ws + OFF_PART);

    __shared__ float4 lkv[KPC*6/4];   // 768 float4 = 12KB
    int tid   = threadIdx.x;
    int chunk = blockIdx.y;
    const float4* src = (const float4*)(ws_kv + chunk*KPC*6);
    #pragma unroll
    for (int i=tid; i<KPC*6/4; i+=256) lkv[i]=src[i];
    __syncthreads();

    int pix = blockIdx.x*256 + tid;
    float4 q = ((const float4*)ws_q)[pix];

    float s=0.0f, a0=0.0f, a1=0.0f, a2=0.0f;
    #pragma unroll 4
    for (int kk=0; kk<KPC/2; ++kk){
        float4 A = lkv[kk*3+0];
        float4 B = lkv[kk*3+1];
        float4 C = lkv[kk*3+2];
        // key pair layout: k0(A.x,A.y,A.z) v0(A.w,B.x,B.y) | k1(B.z,B.w,C.x) v1(C.y,C.z,C.w)
        float l0 = q.x*A.x + q.y*A.y + q.z*A.z;
        float p0 = exp2f(l0);
        s += p0; a0 += p0*A.w; a1 += p0*B.x; a2 += p0*B.y;
        float l1 = q.x*B.z + q.y*B.w + q.z*C.x;
        float p1 = exp2f(l1);
        s += p1; a0 += p1*C.y; a1 += p1*C.z; a2 += p1*C.w;
    }
    ((float4*)ws_part)[chunk*NPIX + pix] = make_float4(s,a0,a1,a2);
}

__global__ __launch_bounds__(256) void k3_final(
    const float* __restrict__ ws,
    const float* __restrict__ mo_w1, const float* __restrict__ mo_b1,
    const float* __restrict__ mo_w2, const float* __restrict__ mo_b2,
    const float* __restrict__ n2_g,  const float* __restrict__ n2_b,
    const float* __restrict__ fuse_w,const float* __restrict__ fuse_b,
    float* __restrict__ out)
{
    const float* ws_eehs = ws + OFF_EEHS;
    const float* ws_mm   = ws + OFF_MM;
    const float* ws_part = ws + OFF_PART;

    int tid = threadIdx.x;
    int pix = blockIdx.x*256 + tid;

    float s=0.0f, a0=0.0f, a1=0.0f, a2=0.0f;
    #pragma unroll
    for (int c=0;c<NC;c++){
        float4 p = ((const float4*)ws_part)[c*NPIX + pix];
        s+=p.x; a0+=p.y; a1+=p.z; a2+=p.w;
    }
    float invs = 1.0f/s;
    float xa0 = a0*invs, xa1 = a1*invs, xa2 = a2*invs;

    // mlp_out
    float h6[6];
    #pragma unroll
    for (int i=0;i<6;i++){
        float a = mo_w1[i*3+0]*xa0 + mo_w1[i*3+1]*xa1 + mo_w1[i*3+2]*xa2 + mo_b1[i];
        h6[i] = gelu_tanh(a);
    }
    float y[3];
    #pragma unroll
    for (int i=0;i<3;i++){
        float a = mo_b2[i];
        #pragma unroll
        for (int k=0;k<6;k++) a += mo_w2[i*6+k]*h6[k];
        y[i]=a;
    }
    float m  = (y[0]+y[1]+y[2])*(1.0f/3.0f);
    float d0 = y[0]-m, d1 = y[1]-m, d2 = y[2]-m;
    float var = (d0*d0+d1*d1+d2*d2)*(1.0f/3.0f);
    float inv = 1.0f/sqrtf(var+1e-5f);
    float t0 = d0*inv*n2_g[0]+n2_b[0];
    float t1 = d1*inv*n2_g[1]+n2_b[1];
    float t2 = d2*inv*n2_g[2]+n2_b[2];

    // PSF: S_n normalize + blend
    float4 e  = ((const float4*)ws_eehs)[pix*2+0];   // EE, S
    float4 hh = ((const float4*)ws_eehs)[pix*2+1];   // HH
    int b = (pix >= HW) ? 1 : 0;
    int base = b*36;
    float mn = INFINITY, mx = -INFINITY;
    for (int i=0;i<36;i++){
        mn = fminf(mn, ws_mm[(base+i)*2+0]);
        mx = fmaxf(mx, ws_mm[(base+i)*2+1]);
    }
    float Sn = (e.w - mn)/(mx - mn);
    float f0 = Sn*e.x + (1.0f-Sn)*hh.x;
    float f1 = Sn*e.y + (1.0f-Sn)*hh.y;
    float f2 = Sn*e.z + (1.0f-Sn)*hh.z;

    int pos = pix - b*HW;
    #pragma unroll
    for (int o=0;o<3;o++){
        float val = fuse_b[o]
                  + fuse_w[o*6+0]*t0 + fuse_w[o*6+1]*t1 + fuse_w[o*6+2]*t2
                  + fuse_w[o*6+3]*f0 + fuse_w[o*6+4]*f1 + fuse_w[o*6+5]*f2;
        out[(b*3+o)*HW + pos] = val;
    }
}

extern "C" void kernel_launch(void* const* d_in, const int* in_sizes, int n_in,
                              void* d_out, int out_size, void* d_ws, size_t ws_size,
                              hipStream_t stream) {
    const float* front  = (const float*)d_in[0];
    const float* back   = (const float*)d_in[1];
    // d_in[2] = mask (unused by reference)
    const float* bg     = (const float*)d_in[3];
    const float* mi_w1  = (const float*)d_in[4];
    const float* mi_b1  = (const float*)d_in[5];
    const float* mi_w2  = (const float*)d_in[6];
    const float* mi_b2  = (const float*)d_in[7];
    const float* q_w    = (const float*)d_in[8];
    const float* k_w    = (const float*)d_in[9];
    const float* v_w    = (const float*)d_in[10];
    const float* mo_w1  = (const float*)d_in[11];
    const float* mo_b1  = (const float*)d_in[12];
    const float* mo_w2  = (const float*)d_in[13];
    const float* mo_b2  = (const float*)d_in[14];
    const float* n1_g   = (const float*)d_in[15];
    const float* n1_b   = (const float*)d_in[16];
    const float* n2_g   = (const float*)d_in[17];
    const float* n2_b   = (const float*)d_in[18];
    const float* e_w    = (const float*)d_in[19];
    const float* e_b    = (const float*)d_in[20];
    const float* f_w    = (const float*)d_in[21];
    const float* f_b    = (const float*)d_in[22];
    const float* g_w    = (const float*)d_in[23];
    const float* g_b    = (const float*)d_in[24];
    const float* h_w    = (const float*)d_in[25];
    const float* h_b    = (const float*)d_in[26];
    const float* fuse_w = (const float*)d_in[27];
    const float* fuse_b = (const float*)d_in[28];

    float* ws  = (float*)d_ws;
    float* out = (float*)d_out;

    k1_prep<<<dim3(NPIX/256), 256, 0, stream>>>(
        front, back, bg, mi_w1, mi_b1, mi_w2, mi_b2, q_w, k_w, v_w,
        n1_g, n1_b, e_w, e_b, f_w, f_b, g_w, g_b, h_w, h_b, ws);

    k2_attn<<<dim3(NPIX/256, NC), 256, 0, stream>>>(ws);

    k3_final<<<dim3(NPIX/256), 256, 0, stream>>>(
        ws, mo_w1, mo_b1, mo_w2, mo_b2, n2_g, n2_b, fuse_w, fuse_b, out);
}